// Round 3
// baseline (110.990 us; speedup 1.0000x reference)
//
#include <hip/hip_runtime.h>
#include <math.h>

#define T 8192
#define D 36
#define NCH 32            // j-chunks
#define CHUNK (T / NCH)   // 256 == blockDim
#define RPT 4             // rows per thread
#define RBLK (T / (256 * RPT))  // 8 row-blocks

// ws layout: partials float2[NCH][2T]  {bestval, as_float(bestidx)}
// indexed [c][head*T + row]  (transposed for coalescing) = 4 MB

__device__ __forceinline__ void dot2_row(const float* __restrict__ E, int row,
                                         const float* __restrict__ W,
                                         float& d0, float& d1) {
    const float4* Er = (const float4*)(E + row * D);  // 144B stride, 16B aligned
    float a0 = 0.f, a1 = 0.f;
#pragma unroll
    for (int i = 0; i < D / 4; ++i) {
        float4 v = Er[i];
        a0 = fmaf(v.x, W[4 * i + 0], a0);
        a0 = fmaf(v.y, W[4 * i + 1], a0);
        a0 = fmaf(v.z, W[4 * i + 2], a0);
        a0 = fmaf(v.w, W[4 * i + 3], a0);
        a1 = fmaf(v.x, W[D + 4 * i + 0], a1);
        a1 = fmaf(v.y, W[D + 4 * i + 1], a1);
        a1 = fmaf(v.z, W[D + 4 * i + 2], a1);
        a1 = fmaf(v.w, W[D + 4 * i + 3], a1);
    }
    d0 = a0; d1 = a1;
}

// grid (RBLK, NCH, 2), block 256
__global__ __launch_bounds__(256, 2) void fused_kernel(
    const float* __restrict__ E,
    const float* __restrict__ WQp, const float* __restrict__ WKp,
    const float* __restrict__ WQs, const float* __restrict__ WKs,
    float2* __restrict__ part) {
    const int head = blockIdx.z;
    const float* WQ = head ? WQs : WQp;
    const float* WK = head ? WKs : WKp;

    __shared__ float2 sk[CHUNK];
    const int j0 = blockIdx.y * CHUNK;

    // stage K-chunk: one row per thread (CHUNK == blockDim)
    {
        float k0, k1;
        dot2_row(E, j0 + (int)threadIdx.x, WK, k0, k1);
        sk[threadIdx.x] = make_float2(k0, k1);
    }

    // this thread's Q rows
    const int rbase = blockIdx.x * (256 * RPT) + threadIdx.x;
    float q0[RPT], q1[RPT];
#pragma unroll
    for (int i = 0; i < RPT; ++i)
        dot2_row(E, rbase + 256 * i, WQ, q0[i], q1[i]);

    __syncthreads();

    // even/odd split: independent chains (SLP -> v_pk_fma_f32), exact
    // first-occurrence restored in the merge below.
    float beste[RPT], besto[RPT];
    int bie[RPT], bio[RPT];
#pragma unroll
    for (int i = 0; i < RPT; ++i) {
        beste[i] = -INFINITY; besto[i] = -INFINITY;
        bie[i] = 0; bio[i] = 1;
    }
#pragma unroll 4
    for (int k = 0; k < CHUNK; k += 2) {
        float2 ke = sk[k];
        float2 ko = sk[k + 1];
#pragma unroll
        for (int i = 0; i < RPT; ++i) {
            float se = fmaf(q0[i], ke.x, q1[i] * ke.y);
            float so = fmaf(q0[i], ko.x, q1[i] * ko.y);
            bool ge = se > beste[i];           // strict > keeps first even occurrence
            beste[i] = ge ? se : beste[i];
            bie[i]   = ge ? k : bie[i];
            bool go = so > besto[i];
            besto[i] = go ? so : besto[i];
            bio[i]   = go ? (k + 1) : bio[i];
        }
    }
#pragma unroll
    for (int i = 0; i < RPT; ++i) {
        bool ogt = besto[i] > beste[i];
        float bv = ogt ? besto[i] : beste[i];
        int bj   = ogt ? bio[i] : bie[i];
        if (beste[i] == besto[i]) bj = min(bie[i], bio[i]);  // tie -> earliest overall
        const int prow = head * T + rbase + 256 * i;
        part[blockIdx.y * (2 * T) + prow] = make_float2(bv, __int_as_float(j0 + bj));
    }
}

__global__ __launch_bounds__(256) void finalize_kernel(
    const float* __restrict__ E,
    const float* __restrict__ WVop, const float* __restrict__ WVarg,
    const float* __restrict__ WVs,
    const float2* __restrict__ part, float* __restrict__ out) {
    int idx = blockIdx.x * 256 + threadIdx.x;  // 0 .. 2T-1
    float best = -INFINITY;
    int bj = 0;
#pragma unroll
    for (int c = 0; c < NCH; ++c) {   // ascending chunk order => first occurrence
        float2 p = part[c * (2 * T) + idx];
        bool gt = p.x > best;
        best = gt ? p.x : best;
        bj   = gt ? __float_as_int(p.y) : bj;
    }
    const int head = idx >> 13;       // uniform per block (256 | 8192)
    const int row  = idx & (T - 1);
    const float4* Er = (const float4*)(E + bj * D);
    float e[D];
#pragma unroll
    for (int i = 0; i < D / 4; ++i) {
        float4 v = Er[i];
        e[4 * i + 0] = v.x; e[4 * i + 1] = v.y;
        e[4 * i + 2] = v.z; e[4 * i + 3] = v.w;
    }
    if (head == 0) {
        float vop = 0.f, varg = 0.f;
#pragma unroll
        for (int d = 0; d < D; ++d) {
            vop  = fmaf(e[d], WVop[d], vop);
            varg = fmaf(e[d], WVarg[d], varg);
        }
        out[row]     = vop;
        out[T + row] = varg;
    } else {
        float vs = 0.f;
#pragma unroll
        for (int d = 0; d < D; ++d) vs = fmaf(e[d], WVs[d], vs);
        out[2 * T + row] = vs;
    }
}

extern "C" void kernel_launch(void* const* d_in, const int* in_sizes, int n_in,
                              void* d_out, int out_size, void* d_ws, size_t ws_size,
                              hipStream_t stream) {
    const float* E     = (const float*)d_in[0];
    const float* WQp   = (const float*)d_in[1];
    const float* WKp   = (const float*)d_in[2];
    const float* WVop  = (const float*)d_in[3];
    const float* WVarg = (const float*)d_in[4];
    const float* WQs   = (const float*)d_in[5];
    const float* WKs   = (const float*)d_in[6];
    const float* WVs   = (const float*)d_in[7];
    float* out = (float*)d_out;

    float2* part = (float2*)d_ws;

    dim3 gF(RBLK, NCH, 2);
    fused_kernel<<<gF, 256, 0, stream>>>(E, WQp, WKp, WQs, WKs, part);

    finalize_kernel<<<(2 * T) / 256, 256, 0, stream>>>(E, WVop, WVarg, WVs, part, out);
}